// Round 11
// baseline (190.642 us; speedup 1.0000x reference)
//
#include <hip/hip_runtime.h>

#define N_NODES 100000
#define N_EDGES 1600000
#define IN_DIM 128
#define HID 64
#define OUT_DIM 64

typedef __attribute__((ext_vector_type(8))) short short8;
typedef __attribute__((ext_vector_type(4))) float f32x4;
union FragU { short8 v; unsigned u[4]; };

__device__ __forceinline__ unsigned bf16r(float f) {   // fp32 -> bf16 bits, RNE
    unsigned u = __float_as_uint(f);
    return (u + 0x7FFFu + ((u >> 16) & 1u)) >> 16;
}
__device__ __forceinline__ float blo(unsigned u) { return __uint_as_float(u << 16); }
__device__ __forceinline__ float bhi(unsigned u) { return __uint_as_float(u & 0xFFFF0000u); }

#define K1_BLOCKS 1563          // ceil(6250 tiles / 4 waves)
#define NB 782                  // coarse buckets: dst >> 7 (128 dsts each)
#define CAP 2432                // per-bucket capacity (mean ~2046, +8.5 sigma)
#define P1_BLOCKS 391           // 4096 edges per pass-1 block
#define P1_EPB 4096
#define GRID_TOTAL (K1_BLOCKS + P1_BLOCKS)   // 1954

// ---------------- Fused K1 (MFMA linear) + P1 (coarse bucket scatter) --------
// ROLE INTERLEAVE: every 5th block (and the last) is P1, so P1 blocks are
// co-resident with K1 from t=0 and their atomic/scatter latency hides under
// K1 compute. K1: W packed to bf16 MFMA fragments once per block in LDS.
// P1: per-edge ranks via LDS atomics; ~300K global returning atomics.
__global__ __launch_bounds__(256) void k1_p1(const float* __restrict__ x,
                                             const float* __restrict__ W,
                                             const float* __restrict__ att,
                                             uint4* __restrict__ h4,
                                             float* __restrict__ s,
                                             float* __restrict__ d,
                                             const int* __restrict__ ei,
                                             int* __restrict__ gcount,
                                             unsigned* __restrict__ ibuf) {
    __shared__ float wsL[IN_DIM], wdL[IN_DIM];
    __shared__ __align__(16) unsigned char shmem[4 * 64 * 17 * 4]; // 17408 B union
    const int tid = threadIdx.x;
    const int bx = blockIdx.x;
    const bool is_p1 = ((bx % 5) == 4) || (bx == GRID_TOTAL - 1);

    if (is_p1) {
        // ---- P1: bucket 4096 edges by dst>>7 ----
        int* cnt  = (int*)shmem;             // [NB]
        int* base = cnt + NB;                // [NB]
        const int blk = (bx == GRID_TOTAL - 1) ? (P1_BLOCKS - 1) : (bx / 5);
        const int e4base = blk * (P1_EPB / 4);
        for (int i = tid; i < NB; i += 256) cnt[i] = 0;
        __syncthreads();
        int pk[4][4];                        // dst | local_rank<<17
#pragma unroll
        for (int c = 0; c < 4; ++c) {
            int i4 = e4base + c * 256 + tid;
            if (i4 < N_EDGES / 4) {
                int4 dv = ((const int4*)(ei + N_EDGES))[i4];
                pk[c][0] = dv.x | (atomicAdd(&cnt[dv.x >> 7], 1) << 17);
                pk[c][1] = dv.y | (atomicAdd(&cnt[dv.y >> 7], 1) << 17);
                pk[c][2] = dv.z | (atomicAdd(&cnt[dv.z >> 7], 1) << 17);
                pk[c][3] = dv.w | (atomicAdd(&cnt[dv.w >> 7], 1) << 17);
            }
        }
        __syncthreads();
        for (int b = tid; b < NB; b += 256) {        // one returning atomic per bucket
            int c = cnt[b];
            base[b] = c ? atomicAdd(&gcount[b], c) : 0;
        }
        __syncthreads();
#pragma unroll
        for (int c = 0; c < 4; ++c) {
            int i4 = e4base + c * 256 + tid;
            if (i4 < N_EDGES / 4) {
                int4 sv = ((const int4*)ei)[i4];
                int srcs[4] = {sv.x, sv.y, sv.z, sv.w};
#pragma unroll
                for (int j = 0; j < 4; ++j) {
                    unsigned p   = (unsigned)pk[c][j];
                    unsigned dst = p & 0x1FFFFu;
                    unsigned r   = p >> 17;
                    unsigned bk  = dst >> 7;
                    ibuf[bk * CAP + (unsigned)base[bk] + r] =
                        (unsigned)srcs[j] | ((dst & 127u) << 20);
                }
            }
        }
        return;
    }
    const int kb = bx - (bx + 1) / 5;        // K1 block id: 0..1562 exactly

    // ---- K1: h(bf16) = x @ W^T via MFMA; s,d exact fp32 from x@(W^T att) ----
    uint4* wlds = (uint4*)shmem;             // [4 t][4 ks][64 lane] = 16384 B
    if (tid < IN_DIM) {
        float as = 0.f, ad = 0.f;
#pragma unroll
        for (int c = 0; c < HID; ++c) {
            float w = W[c * IN_DIM + tid];
            as += w * att[c];
            ad += w * att[HID + c];
        }
        wsL[tid] = as; wdL[tid] = ad;
    }
    // cooperative W -> bf16 fragment pack (once per block, 4 uint4/thread)
    for (int i = tid; i < 1024; i += 256) {
        int ln = i & 63, ks = (i >> 6) & 3, t = i >> 8;
        int fl16 = ln & 15, fq = ln >> 4;
        const float* wp = &W[(t * 16 + fl16) * IN_DIM + ks * 32 + fq * 8];
        float4 wa = *(const float4*)wp;
        float4 wb = *(const float4*)(wp + 4);
        uint4 o;
        o.x = bf16r(wa.x) | (bf16r(wa.y) << 16);
        o.y = bf16r(wa.z) | (bf16r(wa.w) << 16);
        o.z = bf16r(wb.x) | (bf16r(wb.y) << 16);
        o.w = bf16r(wb.z) | (bf16r(wb.w) << 16);
        wlds[i] = o;
    }
    __syncthreads();

    const int lane = tid & 63;
    const int wv = tid >> 6;
    const int l16 = lane & 15;
    const int quad = lane >> 4;
    const int tile = kb * 4 + wv;
    const bool valid = (tile < N_NODES / 16);
    const int rowbase = tile * 16;

    f32x4 acc[4] = {{0.f,0.f,0.f,0.f},{0.f,0.f,0.f,0.f},
                    {0.f,0.f,0.f,0.f},{0.f,0.f,0.f,0.f}};
    float ps = 0.f, pd = 0.f;
    if (valid) {
        const float* xrow = &x[(size_t)(rowbase + l16) * IN_DIM];
#pragma unroll
        for (int ks = 0; ks < 4; ++ks) {
            const int k0 = ks * 32 + quad * 8;
            float4 xa = *(const float4*)&xrow[k0];
            float4 xb = *(const float4*)&xrow[k0 + 4];
            ps += xa.x * wsL[k0]     + xa.y * wsL[k0 + 1]
                + xa.z * wsL[k0 + 2] + xa.w * wsL[k0 + 3]
                + xb.x * wsL[k0 + 4] + xb.y * wsL[k0 + 5]
                + xb.z * wsL[k0 + 6] + xb.w * wsL[k0 + 7];
            pd += xa.x * wdL[k0]     + xa.y * wdL[k0 + 1]
                + xa.z * wdL[k0 + 2] + xa.w * wdL[k0 + 3]
                + xb.x * wdL[k0 + 4] + xb.y * wdL[k0 + 5]
                + xb.z * wdL[k0 + 6] + xb.w * wdL[k0 + 7];
            FragU af;
            af.u[0] = bf16r(xa.x) | (bf16r(xa.y) << 16);
            af.u[1] = bf16r(xa.z) | (bf16r(xa.w) << 16);
            af.u[2] = bf16r(xb.x) | (bf16r(xb.y) << 16);
            af.u[3] = bf16r(xb.z) | (bf16r(xb.w) << 16);
#pragma unroll
            for (int t = 0; t < 4; ++t) {
                FragU bf;
                *(uint4*)&bf = wlds[(t * 4 + ks) * 64 + lane];  // b128, stride-16B
                acc[t] = __builtin_amdgcn_mfma_f32_16x16x32_bf16(
                    af.v, bf.v, acc[t], 0, 0, 0);
            }
        }
        ps += __shfl_xor(ps, 16, 64); ps += __shfl_xor(ps, 32, 64);
        pd += __shfl_xor(pd, 16, 64); pd += __shfl_xor(pd, 32, 64);
        if (quad == 0) { s[rowbase + l16] = ps; d[rowbase + l16] = pd; }
    }
    __syncthreads();   // all wlds reads done -> reuse shmem as scratch

    if (valid) {
        float* sc = (float*)shmem + wv * 64 * 17;   // per-wave [col][row] stride 17
#pragma unroll
        for (int t = 0; t < 4; ++t)
#pragma unroll
            for (int r = 0; r < 4; ++r)
                sc[(l16 + 16 * t) * 17 + quad * 4 + r] = acc[t][r];
        // same-wave RAW through LDS: compiler inserts lgkmcnt wait
#pragma unroll
        for (int i = 0; i < 2; ++i) {
            int idx = i * 64 + lane;
            int nrow = idx >> 3, q = idx & 7;
            float v0 = sc[(q * 8 + 0) * 17 + nrow];
            float v1 = sc[(q * 8 + 1) * 17 + nrow];
            float v2 = sc[(q * 8 + 2) * 17 + nrow];
            float v3 = sc[(q * 8 + 3) * 17 + nrow];
            float v4 = sc[(q * 8 + 4) * 17 + nrow];
            float v5 = sc[(q * 8 + 5) * 17 + nrow];
            float v6 = sc[(q * 8 + 6) * 17 + nrow];
            float v7 = sc[(q * 8 + 7) * 17 + nrow];
            uint4 o;
            o.x = bf16r(v0) | (bf16r(v1) << 16);
            o.y = bf16r(v2) | (bf16r(v3) << 16);
            o.z = bf16r(v4) | (bf16r(v5) << 16);
            o.w = bf16r(v6) | (bf16r(v7) << 16);
            h4[(size_t)(rowbase + nrow) * 8 + q] = o;
        }
    }
}

// ---------------- Fused sort + attention + aggregation + output GEMM ---------
// One block per coarse bucket (~2048 edges, 128 dsts), 512 threads.
// R10 lesson: fixed 2-dst-per-group assignment made wave time = max over 8
// groups (~2x mean) and the el/zloc LDS union forced a block-wide barrier.
// Now: zloc is a SEPARATE LDS buffer (39.4KB total, still 4 blocks/CU since
// threads limit first) and groups pull dsts from a dynamic LDS queue -> wave
// time ~ total-work/8 + tail. W_out fragments still loaded after the gather
// (R9 lesson: VGPR cliff).
__global__ __launch_bounds__(512) void k_sort_agg(const unsigned* __restrict__ ibuf,
                                                  const int* __restrict__ gcount,
                                                  const float* __restrict__ s,
                                                  const float* __restrict__ d,
                                                  const uint4* __restrict__ h4,
                                                  const float* __restrict__ W_out,
                                                  const float* __restrict__ b_out,
                                                  float* __restrict__ out) {
    __shared__ uint2 el[CAP];            // 19456 B: (src, exp-bits) sorted by dst
    __shared__ __align__(16) uint4 zloc4[128 * 9];   // 18432 B: bf16 z rows
    __shared__ int cnt2[128], off2[128];
    __shared__ float dloc[128];
    __shared__ int wred[2];
    __shared__ int qhead;
    const int tid  = threadIdx.x;
    const int lane = tid & 63;
    const int wv   = tid >> 6;
    const int l16  = lane & 15;
    const int quad = lane >> 4;
    const int b    = blockIdx.x;
    const int nodeb = b * 128;

    if (tid < 128) {
        cnt2[tid] = 0;
        int dn = nodeb + tid;
        dloc[tid] = (dn < N_NODES) ? d[dn] : 0.f;
    }
    __syncthreads();
    const int count = gcount[b];

    // pass A: read bucket edges, per-dst ranks via LDS atomics, keep in regs
    unsigned vk[5];
    int rk_[5];
#pragma unroll
    for (int ki = 0; ki < 5; ++ki) {
        int k = tid + ki * 512;
        vk[ki] = 0u; rk_[ki] = -1;
        if (k < count) {
            unsigned v = ibuf[(size_t)b * CAP + k];
            int dl = (int)(v >> 20);
            rk_[ki] = atomicAdd(&cnt2[dl], 1);
            vk[ki] = v;
        }
    }
    __syncthreads();

    // exclusive scan of 128 counters via shfl (2 barriers); cnt2 preserved
    int v0 = 0, sc0 = 0;
    if (tid < 128) {
        v0 = cnt2[tid];
        sc0 = v0;
#pragma unroll
        for (int off = 1; off < 64; off <<= 1) {
            int t = __shfl_up(sc0, off, 64);
            if (lane >= off) sc0 += t;
        }
        if (lane == 63) wred[wv] = sc0;   // wv = 0 or 1 here
    }
    __syncthreads();
    if (tid < 128) {
        int excl = sc0 - v0 + ((wv == 1) ? wred[0] : 0);
        off2[tid] = excl;
    }
    if (tid == 0) qhead = 0;
    __syncthreads();

    // pass B: attention exp + LDS scatter by dst
#pragma unroll
    for (int ki = 0; ki < 5; ++ki) {
        if (rk_[ki] >= 0) {
            unsigned v = vk[ki];
            unsigned src = v & 0xFFFFFu;
            int dl = (int)(v >> 20);
            float e = s[src] + dloc[dl];
            e = (e > 0.f) ? e : 0.2f * e;          // leaky_relu(0.2)
            float ex = __expf(e);                  // shift-invariant
            el[off2[dl] + rk_[ki]] = make_uint2(src, __float_as_uint(ex));
        }
    }
    __syncthreads();

    // aggregation: 64 groups of 8 lanes pull dsts from a dynamic queue.
    // Each lane owns 8 output columns -> no cross-lane reduction. A group
    // writes its z row to zloc the moment the dst finishes (no union barrier).
    const int l8 = tid & 7;
    for (;;) {
        int mydst = 0;
        if (l8 == 0) mydst = atomicAdd(&qhead, 1);
        mydst = __shfl(mydst, lane & 56, 64);      // broadcast from group leader
        if (mydst >= 128) break;
        const int o = off2[mydst];
        const int n = cnt2[mydst];                 // 0 for dsts >= N_NODES
        float a0 = 0.f, a1 = 0.f, a2 = 0.f, a3 = 0.f;
        float a4 = 0.f, a5 = 0.f, a6 = 0.f, a7 = 0.f, se = 0.f;
        int j = 0;
        for (; j + 7 < n; j += 8) {        // 8 gathers in flight
            uint2 r0 = el[o + j];
            uint2 r1 = el[o + j + 1];
            uint2 r2 = el[o + j + 2];
            uint2 r3 = el[o + j + 3];
            uint2 r4 = el[o + j + 4];
            uint2 r5 = el[o + j + 5];
            uint2 r6 = el[o + j + 6];
            uint2 r7 = el[o + j + 7];
            uint4 g0 = h4[(size_t)r0.x * 8u + l8];
            uint4 g1 = h4[(size_t)r1.x * 8u + l8];
            uint4 g2 = h4[(size_t)r2.x * 8u + l8];
            uint4 g3 = h4[(size_t)r3.x * 8u + l8];
            uint4 g4 = h4[(size_t)r4.x * 8u + l8];
            uint4 g5 = h4[(size_t)r5.x * 8u + l8];
            uint4 g6 = h4[(size_t)r6.x * 8u + l8];
            uint4 g7 = h4[(size_t)r7.x * 8u + l8];
            float e0 = __uint_as_float(r0.y), e1 = __uint_as_float(r1.y);
            float e2 = __uint_as_float(r2.y), e3 = __uint_as_float(r3.y);
            float e4 = __uint_as_float(r4.y), e5 = __uint_as_float(r5.y);
            float e6 = __uint_as_float(r6.y), e7 = __uint_as_float(r7.y);
            se += ((e0 + e1) + (e2 + e3)) + ((e4 + e5) + (e6 + e7));
            a0 += e0 * blo(g0.x) + e1 * blo(g1.x) + e2 * blo(g2.x) + e3 * blo(g3.x)
                + e4 * blo(g4.x) + e5 * blo(g5.x) + e6 * blo(g6.x) + e7 * blo(g7.x);
            a1 += e0 * bhi(g0.x) + e1 * bhi(g1.x) + e2 * bhi(g2.x) + e3 * bhi(g3.x)
                + e4 * bhi(g4.x) + e5 * bhi(g5.x) + e6 * bhi(g6.x) + e7 * bhi(g7.x);
            a2 += e0 * blo(g0.y) + e1 * blo(g1.y) + e2 * blo(g2.y) + e3 * blo(g3.y)
                + e4 * blo(g4.y) + e5 * blo(g5.y) + e6 * blo(g6.y) + e7 * blo(g7.y);
            a3 += e0 * bhi(g0.y) + e1 * bhi(g1.y) + e2 * bhi(g2.y) + e3 * bhi(g3.y)
                + e4 * bhi(g4.y) + e5 * bhi(g5.y) + e6 * bhi(g6.y) + e7 * bhi(g7.y);
            a4 += e0 * blo(g0.z) + e1 * blo(g1.z) + e2 * blo(g2.z) + e3 * blo(g3.z)
                + e4 * blo(g4.z) + e5 * blo(g5.z) + e6 * blo(g6.z) + e7 * blo(g7.z);
            a5 += e0 * bhi(g0.z) + e1 * bhi(g1.z) + e2 * bhi(g2.z) + e3 * bhi(g3.z)
                + e4 * bhi(g4.z) + e5 * bhi(g5.z) + e6 * bhi(g6.z) + e7 * bhi(g7.z);
            a6 += e0 * blo(g0.w) + e1 * blo(g1.w) + e2 * blo(g2.w) + e3 * blo(g3.w)
                + e4 * blo(g4.w) + e5 * blo(g5.w) + e6 * blo(g6.w) + e7 * blo(g7.w);
            a7 += e0 * bhi(g0.w) + e1 * bhi(g1.w) + e2 * bhi(g2.w) + e3 * bhi(g3.w)
                + e4 * bhi(g4.w) + e5 * bhi(g5.w) + e6 * bhi(g6.w) + e7 * bhi(g7.w);
        }
        if (j + 3 < n) {
            uint2 r0 = el[o + j];
            uint2 r1 = el[o + j + 1];
            uint2 r2 = el[o + j + 2];
            uint2 r3 = el[o + j + 3];
            uint4 g0 = h4[(size_t)r0.x * 8u + l8];
            uint4 g1 = h4[(size_t)r1.x * 8u + l8];
            uint4 g2 = h4[(size_t)r2.x * 8u + l8];
            uint4 g3 = h4[(size_t)r3.x * 8u + l8];
            float e0 = __uint_as_float(r0.y), e1 = __uint_as_float(r1.y);
            float e2 = __uint_as_float(r2.y), e3 = __uint_as_float(r3.y);
            se += (e0 + e1) + (e2 + e3);
            a0 += e0 * blo(g0.x) + e1 * blo(g1.x) + e2 * blo(g2.x) + e3 * blo(g3.x);
            a1 += e0 * bhi(g0.x) + e1 * bhi(g1.x) + e2 * bhi(g2.x) + e3 * bhi(g3.x);
            a2 += e0 * blo(g0.y) + e1 * blo(g1.y) + e2 * blo(g2.y) + e3 * blo(g3.y);
            a3 += e0 * bhi(g0.y) + e1 * bhi(g1.y) + e2 * bhi(g2.y) + e3 * bhi(g3.y);
            a4 += e0 * blo(g0.z) + e1 * blo(g1.z) + e2 * blo(g2.z) + e3 * blo(g3.z);
            a5 += e0 * bhi(g0.z) + e1 * bhi(g1.z) + e2 * bhi(g2.z) + e3 * bhi(g3.z);
            a6 += e0 * blo(g0.w) + e1 * blo(g1.w) + e2 * blo(g2.w) + e3 * blo(g3.w);
            a7 += e0 * bhi(g0.w) + e1 * bhi(g1.w) + e2 * bhi(g2.w) + e3 * bhi(g3.w);
            j += 4;
        }
        for (; j < n; ++j) {
            uint2 r = el[o + j];
            uint4 gg = h4[(size_t)r.x * 8u + l8];
            float e = __uint_as_float(r.y);
            se += e;
            a0 += e * blo(gg.x); a1 += e * bhi(gg.x);
            a2 += e * blo(gg.y); a3 += e * bhi(gg.y);
            a4 += e * blo(gg.z); a5 += e * bhi(gg.z);
            a6 += e * blo(gg.w); a7 += e * bhi(gg.w);
        }
        float inv = 1.f / (se + 1e-9f);
        uint4 o4;
        o4.x = bf16r(fmaxf(a0 * inv, 0.f)) | (bf16r(fmaxf(a1 * inv, 0.f)) << 16);
        o4.y = bf16r(fmaxf(a2 * inv, 0.f)) | (bf16r(fmaxf(a3 * inv, 0.f)) << 16);
        o4.z = bf16r(fmaxf(a4 * inv, 0.f)) | (bf16r(fmaxf(a5 * inv, 0.f)) << 16);
        o4.w = bf16r(fmaxf(a6 * inv, 0.f)) | (bf16r(fmaxf(a7 * inv, 0.f)) << 16);
        zloc4[mydst * 9 + l8] = o4;        // z row done -> LDS immediately
    }
    __syncthreads();   // all z rows staged
    __builtin_amdgcn_sched_barrier(0);     // keep W_out loads BELOW the gather

    // W_out -> bf16 B-fragments in regs — loaded after gather regs die
    FragU wfrag[4][2];
#pragma unroll
    for (int t = 0; t < 4; ++t)
#pragma unroll
        for (int ks = 0; ks < 2; ++ks) {
            const float* wp = &W_out[(t * 16 + l16) * HID + ks * 32 + quad * 8];
            float4 wa = *(const float4*)wp;
            float4 wb = *(const float4*)(wp + 4);
            wfrag[t][ks].u[0] = bf16r(wa.x) | (bf16r(wa.y) << 16);
            wfrag[t][ks].u[1] = bf16r(wa.z) | (bf16r(wa.w) << 16);
            wfrag[t][ks].u[2] = bf16r(wb.x) | (bf16r(wb.y) << 16);
            wfrag[t][ks].u[3] = bf16r(wb.z) | (bf16r(wb.w) << 16);
        }
    float bias[4];
#pragma unroll
    for (int t = 0; t < 4; ++t) bias[t] = b_out[t * 16 + l16];

    // output GEMM: wave wv owns rows [wv*16, wv*16+16); 4 col-tiles x K=64
    f32x4 oacc[4] = {{0.f,0.f,0.f,0.f},{0.f,0.f,0.f,0.f},
                     {0.f,0.f,0.f,0.f},{0.f,0.f,0.f,0.f}};
#pragma unroll
    for (int ks = 0; ks < 2; ++ks) {
        FragU za;
        *(uint4*)&za = zloc4[(wv * 16 + l16) * 9 + ks * 4 + quad];
#pragma unroll
        for (int t = 0; t < 4; ++t)
            oacc[t] = __builtin_amdgcn_mfma_f32_16x16x32_bf16(
                za.v, wfrag[t][ks].v, oacc[t], 0, 0, 0);
    }
#pragma unroll
    for (int t = 0; t < 4; ++t) {
#pragma unroll
        for (int r = 0; r < 4; ++r) {
            int node = nodeb + wv * 16 + quad * 4 + r;
            if (node < N_NODES)
                out[(size_t)node * OUT_DIM + t * 16 + l16] = oacc[t][r] + bias[t];
        }
    }
}

extern "C" void kernel_launch(void* const* d_in, const int* in_sizes, int n_in,
                              void* d_out, int out_size, void* d_ws, size_t ws_size,
                              hipStream_t stream) {
    const float* x     = (const float*)d_in[0];
    const int*   ei    = (const int*)d_in[1];
    const float* W_lin = (const float*)d_in[2];
    const float* att   = (const float*)d_in[3];
    const float* W_out = (const float*)d_in[4];
    const float* b_out = (const float*)d_in[5];
    float* out = (float*)d_out;

    // workspace layout (~22.4 MB): zp eliminated (out written directly).
    char* ws = (char*)d_ws;
    unsigned* h2        = (unsigned*)(ws);                    // 12,800,000 B (bf16 h)
    float*    s         = (float*)(ws + 12800000);            //    400,000 B
    float*    d         = (float*)(ws + 13200000);            //    400,000 B
    int*      gcount    = (int*)  (ws + 13600000);            //      3,128 B
    unsigned* ibuf      = (unsigned*)(ws + 14800016);         //  7,607,296 B

    hipMemsetAsync(gcount, 0, NB * sizeof(int), stream);

    k1_p1<<<GRID_TOTAL, 256, 0, stream>>>(
        x, W_lin, att, (uint4*)h2, s, d, ei, gcount, ibuf);
    k_sort_agg<<<NB, 512, 0, stream>>>(ibuf, gcount, s, d, (const uint4*)h2,
                                       W_out, b_out, out);
}

// Round 12
// 185.101 us; speedup vs baseline: 1.0299x; 1.0299x over previous
//
#include <hip/hip_runtime.h>

#define N_NODES 100000
#define N_EDGES 1600000
#define IN_DIM 128
#define HID 64
#define OUT_DIM 64

typedef __attribute__((ext_vector_type(8))) short short8;
typedef __attribute__((ext_vector_type(4))) float f32x4;
union FragU { short8 v; unsigned u[4]; };

__device__ __forceinline__ unsigned bf16r(float f) {   // fp32 -> bf16 bits, RNE
    unsigned u = __float_as_uint(f);
    return (u + 0x7FFFu + ((u >> 16) & 1u)) >> 16;
}
__device__ __forceinline__ float blo(unsigned u) { return __uint_as_float(u << 16); }
__device__ __forceinline__ float bhi(unsigned u) { return __uint_as_float(u & 0xFFFF0000u); }

#define K1_BLOCKS 1563          // ceil(6250 tiles / 4 waves)
#define NB 782                  // coarse buckets: dst >> 7 (128 dsts each)
#define CAP 2432                // per-bucket capacity (mean ~2046, +8.5 sigma)
#define P1_BLOCKS 391           // 4096 edges per pass-1 block
#define P1_EPB 4096
#define GRID_TOTAL (K1_BLOCKS + P1_BLOCKS)   // 1954

// ---------------- Fused K1 (MFMA linear) + P1 (coarse bucket scatter) --------
// ROLE INTERLEAVE: every 5th block (and the last) is P1, so P1 blocks are
// co-resident with K1 from t=0 and their atomic/scatter latency hides under
// K1 compute. K1: W packed to bf16 MFMA fragments once per block in LDS.
// P1: per-edge ranks via LDS atomics; ~300K global returning atomics.
__global__ __launch_bounds__(256) void k1_p1(const float* __restrict__ x,
                                             const float* __restrict__ W,
                                             const float* __restrict__ att,
                                             uint4* __restrict__ h4,
                                             float* __restrict__ s,
                                             float* __restrict__ d,
                                             const int* __restrict__ ei,
                                             int* __restrict__ gcount,
                                             unsigned* __restrict__ ibuf) {
    __shared__ float wsL[IN_DIM], wdL[IN_DIM];
    __shared__ __align__(16) unsigned char shmem[4 * 64 * 17 * 4]; // 17408 B union
    const int tid = threadIdx.x;
    const int bx = blockIdx.x;
    const bool is_p1 = ((bx % 5) == 4) || (bx == GRID_TOTAL - 1);

    if (is_p1) {
        // ---- P1: bucket 4096 edges by dst>>7 ----
        int* cnt  = (int*)shmem;             // [NB]
        int* base = cnt + NB;                // [NB]
        const int blk = (bx == GRID_TOTAL - 1) ? (P1_BLOCKS - 1) : (bx / 5);
        const int e4base = blk * (P1_EPB / 4);
        for (int i = tid; i < NB; i += 256) cnt[i] = 0;
        __syncthreads();
        int pk[4][4];                        // dst | local_rank<<17
#pragma unroll
        for (int c = 0; c < 4; ++c) {
            int i4 = e4base + c * 256 + tid;
            if (i4 < N_EDGES / 4) {
                int4 dv = ((const int4*)(ei + N_EDGES))[i4];
                pk[c][0] = dv.x | (atomicAdd(&cnt[dv.x >> 7], 1) << 17);
                pk[c][1] = dv.y | (atomicAdd(&cnt[dv.y >> 7], 1) << 17);
                pk[c][2] = dv.z | (atomicAdd(&cnt[dv.z >> 7], 1) << 17);
                pk[c][3] = dv.w | (atomicAdd(&cnt[dv.w >> 7], 1) << 17);
            }
        }
        __syncthreads();
        for (int b = tid; b < NB; b += 256) {        // one returning atomic per bucket
            int c = cnt[b];
            base[b] = c ? atomicAdd(&gcount[b], c) : 0;
        }
        __syncthreads();
#pragma unroll
        for (int c = 0; c < 4; ++c) {
            int i4 = e4base + c * 256 + tid;
            if (i4 < N_EDGES / 4) {
                int4 sv = ((const int4*)ei)[i4];
                int srcs[4] = {sv.x, sv.y, sv.z, sv.w};
#pragma unroll
                for (int j = 0; j < 4; ++j) {
                    unsigned p   = (unsigned)pk[c][j];
                    unsigned dst = p & 0x1FFFFu;
                    unsigned r   = p >> 17;
                    unsigned bk  = dst >> 7;
                    ibuf[bk * CAP + (unsigned)base[bk] + r] =
                        (unsigned)srcs[j] | ((dst & 127u) << 20);
                }
            }
        }
        return;
    }
    const int kb = bx - (bx + 1) / 5;        // K1 block id: 0..1562 exactly

    // ---- K1: h(bf16) = x @ W^T via MFMA; s,d exact fp32 from x@(W^T att) ----
    uint4* wlds = (uint4*)shmem;             // [4 t][4 ks][64 lane] = 16384 B
    if (tid < IN_DIM) {
        float as = 0.f, ad = 0.f;
#pragma unroll
        for (int c = 0; c < HID; ++c) {
            float w = W[c * IN_DIM + tid];
            as += w * att[c];
            ad += w * att[HID + c];
        }
        wsL[tid] = as; wdL[tid] = ad;
    }
    // cooperative W -> bf16 fragment pack (once per block, 4 uint4/thread)
    for (int i = tid; i < 1024; i += 256) {
        int ln = i & 63, ks = (i >> 6) & 3, t = i >> 8;
        int fl16 = ln & 15, fq = ln >> 4;
        const float* wp = &W[(t * 16 + fl16) * IN_DIM + ks * 32 + fq * 8];
        float4 wa = *(const float4*)wp;
        float4 wb = *(const float4*)(wp + 4);
        uint4 o;
        o.x = bf16r(wa.x) | (bf16r(wa.y) << 16);
        o.y = bf16r(wa.z) | (bf16r(wa.w) << 16);
        o.z = bf16r(wb.x) | (bf16r(wb.y) << 16);
        o.w = bf16r(wb.z) | (bf16r(wb.w) << 16);
        wlds[i] = o;
    }
    __syncthreads();

    const int lane = tid & 63;
    const int wv = tid >> 6;
    const int l16 = lane & 15;
    const int quad = lane >> 4;
    const int tile = kb * 4 + wv;
    const bool valid = (tile < N_NODES / 16);
    const int rowbase = tile * 16;

    f32x4 acc[4] = {{0.f,0.f,0.f,0.f},{0.f,0.f,0.f,0.f},
                    {0.f,0.f,0.f,0.f},{0.f,0.f,0.f,0.f}};
    float ps = 0.f, pd = 0.f;
    if (valid) {
        const float* xrow = &x[(size_t)(rowbase + l16) * IN_DIM];
#pragma unroll
        for (int ks = 0; ks < 4; ++ks) {
            const int k0 = ks * 32 + quad * 8;
            float4 xa = *(const float4*)&xrow[k0];
            float4 xb = *(const float4*)&xrow[k0 + 4];
            ps += xa.x * wsL[k0]     + xa.y * wsL[k0 + 1]
                + xa.z * wsL[k0 + 2] + xa.w * wsL[k0 + 3]
                + xb.x * wsL[k0 + 4] + xb.y * wsL[k0 + 5]
                + xb.z * wsL[k0 + 6] + xb.w * wsL[k0 + 7];
            pd += xa.x * wdL[k0]     + xa.y * wdL[k0 + 1]
                + xa.z * wdL[k0 + 2] + xa.w * wdL[k0 + 3]
                + xb.x * wdL[k0 + 4] + xb.y * wdL[k0 + 5]
                + xb.z * wdL[k0 + 6] + xb.w * wdL[k0 + 7];
            FragU af;
            af.u[0] = bf16r(xa.x) | (bf16r(xa.y) << 16);
            af.u[1] = bf16r(xa.z) | (bf16r(xa.w) << 16);
            af.u[2] = bf16r(xb.x) | (bf16r(xb.y) << 16);
            af.u[3] = bf16r(xb.z) | (bf16r(xb.w) << 16);
#pragma unroll
            for (int t = 0; t < 4; ++t) {
                FragU bf;
                *(uint4*)&bf = wlds[(t * 4 + ks) * 64 + lane];  // b128, stride-16B
                acc[t] = __builtin_amdgcn_mfma_f32_16x16x32_bf16(
                    af.v, bf.v, acc[t], 0, 0, 0);
            }
        }
        ps += __shfl_xor(ps, 16, 64); ps += __shfl_xor(ps, 32, 64);
        pd += __shfl_xor(pd, 16, 64); pd += __shfl_xor(pd, 32, 64);
        if (quad == 0) { s[rowbase + l16] = ps; d[rowbase + l16] = pd; }
    }
    __syncthreads();   // all wlds reads done -> reuse shmem as scratch

    if (valid) {
        float* sc = (float*)shmem + wv * 64 * 17;   // per-wave [col][row] stride 17
#pragma unroll
        for (int t = 0; t < 4; ++t)
#pragma unroll
            for (int r = 0; r < 4; ++r)
                sc[(l16 + 16 * t) * 17 + quad * 4 + r] = acc[t][r];
        // same-wave RAW through LDS: compiler inserts lgkmcnt wait
#pragma unroll
        for (int i = 0; i < 2; ++i) {
            int idx = i * 64 + lane;
            int nrow = idx >> 3, q = idx & 7;
            float v0 = sc[(q * 8 + 0) * 17 + nrow];
            float v1 = sc[(q * 8 + 1) * 17 + nrow];
            float v2 = sc[(q * 8 + 2) * 17 + nrow];
            float v3 = sc[(q * 8 + 3) * 17 + nrow];
            float v4 = sc[(q * 8 + 4) * 17 + nrow];
            float v5 = sc[(q * 8 + 5) * 17 + nrow];
            float v6 = sc[(q * 8 + 6) * 17 + nrow];
            float v7 = sc[(q * 8 + 7) * 17 + nrow];
            uint4 o;
            o.x = bf16r(v0) | (bf16r(v1) << 16);
            o.y = bf16r(v2) | (bf16r(v3) << 16);
            o.z = bf16r(v4) | (bf16r(v5) << 16);
            o.w = bf16r(v6) | (bf16r(v7) << 16);
            h4[(size_t)(rowbase + nrow) * 8 + q] = o;
        }
    }
}

// ---------------- Fused sort + attention + aggregation + output GEMM ---------
// One block per coarse bucket (~2048 edges, 128 dsts), 512 threads.
// R11 lesson: the block-wide barrier before the GEMM epilogue serialized a
// multi-us tail per block (R7 without epilogue: 45.8us; R10/R11 with: 62-64).
// Now: wave wv OWNS dsts [wv*16, wv*16+16) — its epilogue MFMA reads exactly
// the zloc rows it wrote, so the gather->GEMM barrier is GONE. Fast waves run
// their W_out pack + GEMM + stores while slow waves still gather. Same-wave
// LDS write->read ordered by s_waitcnt lgkmcnt(0) + sched_barrier (rule #18).
__global__ __launch_bounds__(512) void k_sort_agg(const unsigned* __restrict__ ibuf,
                                                  const int* __restrict__ gcount,
                                                  const float* __restrict__ s,
                                                  const float* __restrict__ d,
                                                  const uint4* __restrict__ h4,
                                                  const float* __restrict__ W_out,
                                                  const float* __restrict__ b_out,
                                                  float* __restrict__ out) {
    __shared__ uint2 el[CAP];            // 19456 B: (src, exp-bits) sorted by dst
    __shared__ __align__(16) uint4 zloc4[128 * 9];   // 18432 B: bf16 z rows
    __shared__ int cnt2[128], off2[128];
    __shared__ float dloc[128];
    __shared__ int wred[2];
    const int tid  = threadIdx.x;
    const int lane = tid & 63;
    const int wv   = tid >> 6;
    const int l16  = lane & 15;
    const int quad = lane >> 4;
    const int b    = blockIdx.x;
    const int nodeb = b * 128;

    if (tid < 128) {
        cnt2[tid] = 0;
        int dn = nodeb + tid;
        dloc[tid] = (dn < N_NODES) ? d[dn] : 0.f;
    }
    __syncthreads();
    const int count = gcount[b];

    // pass A: read bucket edges, per-dst ranks via LDS atomics, keep in regs
    unsigned vk[5];
    int rk_[5];
#pragma unroll
    for (int ki = 0; ki < 5; ++ki) {
        int k = tid + ki * 512;
        vk[ki] = 0u; rk_[ki] = -1;
        if (k < count) {
            unsigned v = ibuf[(size_t)b * CAP + k];
            int dl = (int)(v >> 20);
            rk_[ki] = atomicAdd(&cnt2[dl], 1);
            vk[ki] = v;
        }
    }
    __syncthreads();

    // exclusive scan of 128 counters via shfl (2 barriers); cnt2 preserved
    int v0 = 0, sc0 = 0;
    if (tid < 128) {
        v0 = cnt2[tid];
        sc0 = v0;
#pragma unroll
        for (int off = 1; off < 64; off <<= 1) {
            int t = __shfl_up(sc0, off, 64);
            if (lane >= off) sc0 += t;
        }
        if (lane == 63) wred[wv] = sc0;   // wv = 0 or 1 here
    }
    __syncthreads();
    if (tid < 128) {
        int excl = sc0 - v0 + ((wv == 1) ? wred[0] : 0);
        off2[tid] = excl;
    }
    __syncthreads();

    // pass B: attention exp + LDS scatter by dst
#pragma unroll
    for (int ki = 0; ki < 5; ++ki) {
        if (rk_[ki] >= 0) {
            unsigned v = vk[ki];
            unsigned src = v & 0xFFFFFu;
            int dl = (int)(v >> 20);
            float e = s[src] + dloc[dl];
            e = (e > 0.f) ? e : 0.2f * e;          // leaky_relu(0.2)
            float ex = __expf(e);                  // shift-invariant
            el[off2[dl] + rk_[ki]] = make_uint2(src, __float_as_uint(ex));
        }
    }
    __syncthreads();   // LAST block barrier: el now read-only, waves independent

    // aggregation: wave wv owns dsts [wv*16, wv*16+16); 8 groups of 8 lanes,
    // group gl handles dsts wv*16+gl and wv*16+gl+8. Each lane owns 8 output
    // columns -> no cross-lane reduction, and all 16 zloc rows the wave's
    // epilogue needs are produced by this wave -> no barrier before GEMM.
    const int l8 = tid & 7;
    const int gl = lane >> 3;
#pragma unroll
    for (int half = 0; half < 2; ++half) {
        const int dl = wv * 16 + gl + half * 8;
        const int o = off2[dl];
        const int n = cnt2[dl];                 // 0 for dsts >= N_NODES
        float a0 = 0.f, a1 = 0.f, a2 = 0.f, a3 = 0.f;
        float a4 = 0.f, a5 = 0.f, a6 = 0.f, a7 = 0.f, se = 0.f;
        int j = 0;
        for (; j + 7 < n; j += 8) {        // 8 gathers in flight
            uint2 r0 = el[o + j];
            uint2 r1 = el[o + j + 1];
            uint2 r2 = el[o + j + 2];
            uint2 r3 = el[o + j + 3];
            uint2 r4 = el[o + j + 4];
            uint2 r5 = el[o + j + 5];
            uint2 r6 = el[o + j + 6];
            uint2 r7 = el[o + j + 7];
            uint4 g0 = h4[(size_t)r0.x * 8u + l8];
            uint4 g1 = h4[(size_t)r1.x * 8u + l8];
            uint4 g2 = h4[(size_t)r2.x * 8u + l8];
            uint4 g3 = h4[(size_t)r3.x * 8u + l8];
            uint4 g4 = h4[(size_t)r4.x * 8u + l8];
            uint4 g5 = h4[(size_t)r5.x * 8u + l8];
            uint4 g6 = h4[(size_t)r6.x * 8u + l8];
            uint4 g7 = h4[(size_t)r7.x * 8u + l8];
            float e0 = __uint_as_float(r0.y), e1 = __uint_as_float(r1.y);
            float e2 = __uint_as_float(r2.y), e3 = __uint_as_float(r3.y);
            float e4 = __uint_as_float(r4.y), e5 = __uint_as_float(r5.y);
            float e6 = __uint_as_float(r6.y), e7 = __uint_as_float(r7.y);
            se += ((e0 + e1) + (e2 + e3)) + ((e4 + e5) + (e6 + e7));
            a0 += e0 * blo(g0.x) + e1 * blo(g1.x) + e2 * blo(g2.x) + e3 * blo(g3.x)
                + e4 * blo(g4.x) + e5 * blo(g5.x) + e6 * blo(g6.x) + e7 * blo(g7.x);
            a1 += e0 * bhi(g0.x) + e1 * bhi(g1.x) + e2 * bhi(g2.x) + e3 * bhi(g3.x)
                + e4 * bhi(g4.x) + e5 * bhi(g5.x) + e6 * bhi(g6.x) + e7 * bhi(g7.x);
            a2 += e0 * blo(g0.y) + e1 * blo(g1.y) + e2 * blo(g2.y) + e3 * blo(g3.y)
                + e4 * blo(g4.y) + e5 * blo(g5.y) + e6 * blo(g6.y) + e7 * blo(g7.y);
            a3 += e0 * bhi(g0.y) + e1 * bhi(g1.y) + e2 * bhi(g2.y) + e3 * bhi(g3.y)
                + e4 * bhi(g4.y) + e5 * bhi(g5.y) + e6 * bhi(g6.y) + e7 * bhi(g7.y);
            a4 += e0 * blo(g0.z) + e1 * blo(g1.z) + e2 * blo(g2.z) + e3 * blo(g3.z)
                + e4 * blo(g4.z) + e5 * blo(g5.z) + e6 * blo(g6.z) + e7 * blo(g7.z);
            a5 += e0 * bhi(g0.z) + e1 * bhi(g1.z) + e2 * bhi(g2.z) + e3 * bhi(g3.z)
                + e4 * bhi(g4.z) + e5 * bhi(g5.z) + e6 * bhi(g6.z) + e7 * bhi(g7.z);
            a6 += e0 * blo(g0.w) + e1 * blo(g1.w) + e2 * blo(g2.w) + e3 * blo(g3.w)
                + e4 * blo(g4.w) + e5 * blo(g5.w) + e6 * blo(g6.w) + e7 * blo(g7.w);
            a7 += e0 * bhi(g0.w) + e1 * bhi(g1.w) + e2 * bhi(g2.w) + e3 * bhi(g3.w)
                + e4 * bhi(g4.w) + e5 * bhi(g5.w) + e6 * bhi(g6.w) + e7 * bhi(g7.w);
        }
        if (j + 3 < n) {
            uint2 r0 = el[o + j];
            uint2 r1 = el[o + j + 1];
            uint2 r2 = el[o + j + 2];
            uint2 r3 = el[o + j + 3];
            uint4 g0 = h4[(size_t)r0.x * 8u + l8];
            uint4 g1 = h4[(size_t)r1.x * 8u + l8];
            uint4 g2 = h4[(size_t)r2.x * 8u + l8];
            uint4 g3 = h4[(size_t)r3.x * 8u + l8];
            float e0 = __uint_as_float(r0.y), e1 = __uint_as_float(r1.y);
            float e2 = __uint_as_float(r2.y), e3 = __uint_as_float(r3.y);
            se += (e0 + e1) + (e2 + e3);
            a0 += e0 * blo(g0.x) + e1 * blo(g1.x) + e2 * blo(g2.x) + e3 * blo(g3.x);
            a1 += e0 * bhi(g0.x) + e1 * bhi(g1.x) + e2 * bhi(g2.x) + e3 * bhi(g3.x);
            a2 += e0 * blo(g0.y) + e1 * blo(g1.y) + e2 * blo(g2.y) + e3 * blo(g3.y);
            a3 += e0 * bhi(g0.y) + e1 * bhi(g1.y) + e2 * bhi(g2.y) + e3 * bhi(g3.y);
            a4 += e0 * blo(g0.z) + e1 * blo(g1.z) + e2 * blo(g2.z) + e3 * blo(g3.z);
            a5 += e0 * bhi(g0.z) + e1 * bhi(g1.z) + e2 * bhi(g2.z) + e3 * bhi(g3.z);
            a6 += e0 * blo(g0.w) + e1 * blo(g1.w) + e2 * blo(g2.w) + e3 * blo(g3.w);
            a7 += e0 * bhi(g0.w) + e1 * bhi(g1.w) + e2 * bhi(g2.w) + e3 * bhi(g3.w);
            j += 4;
        }
        for (; j < n; ++j) {
            uint2 r = el[o + j];
            uint4 gg = h4[(size_t)r.x * 8u + l8];
            float e = __uint_as_float(r.y);
            se += e;
            a0 += e * blo(gg.x); a1 += e * bhi(gg.x);
            a2 += e * blo(gg.y); a3 += e * bhi(gg.y);
            a4 += e * blo(gg.z); a5 += e * bhi(gg.z);
            a6 += e * blo(gg.w); a7 += e * bhi(gg.w);
        }
        float inv = 1.f / (se + 1e-9f);
        uint4 o4;
        o4.x = bf16r(fmaxf(a0 * inv, 0.f)) | (bf16r(fmaxf(a1 * inv, 0.f)) << 16);
        o4.y = bf16r(fmaxf(a2 * inv, 0.f)) | (bf16r(fmaxf(a3 * inv, 0.f)) << 16);
        o4.z = bf16r(fmaxf(a4 * inv, 0.f)) | (bf16r(fmaxf(a5 * inv, 0.f)) << 16);
        o4.w = bf16r(fmaxf(a6 * inv, 0.f)) | (bf16r(fmaxf(a7 * inv, 0.f)) << 16);
        zloc4[dl * 9 + l8] = o4;           // z row -> LDS (this wave's rows only)
    }
    // same-wave LDS writes must land before this wave's zloc reads (rule #18)
    asm volatile("s_waitcnt lgkmcnt(0)" ::: "memory");
    __builtin_amdgcn_sched_barrier(0);

    // W_out -> bf16 B-fragments in regs — after gather regs die (R9 lesson)
    FragU wfrag[4][2];
#pragma unroll
    for (int t = 0; t < 4; ++t)
#pragma unroll
        for (int ks = 0; ks < 2; ++ks) {
            const float* wp = &W_out[(t * 16 + l16) * HID + ks * 32 + quad * 8];
            float4 wa = *(const float4*)wp;
            float4 wb = *(const float4*)(wp + 4);
            wfrag[t][ks].u[0] = bf16r(wa.x) | (bf16r(wa.y) << 16);
            wfrag[t][ks].u[1] = bf16r(wa.z) | (bf16r(wa.w) << 16);
            wfrag[t][ks].u[2] = bf16r(wb.x) | (bf16r(wb.y) << 16);
            wfrag[t][ks].u[3] = bf16r(wb.z) | (bf16r(wb.w) << 16);
        }
    float bias[4];
#pragma unroll
    for (int t = 0; t < 4; ++t) bias[t] = b_out[t * 16 + l16];

    // per-wave output GEMM: rows [wv*16, wv*16+16); 4 col-tiles x K=64
    f32x4 oacc[4] = {{0.f,0.f,0.f,0.f},{0.f,0.f,0.f,0.f},
                     {0.f,0.f,0.f,0.f},{0.f,0.f,0.f,0.f}};
#pragma unroll
    for (int ks = 0; ks < 2; ++ks) {
        FragU za;
        *(uint4*)&za = zloc4[(wv * 16 + l16) * 9 + ks * 4 + quad];
#pragma unroll
        for (int t = 0; t < 4; ++t)
            oacc[t] = __builtin_amdgcn_mfma_f32_16x16x32_bf16(
                za.v, wfrag[t][ks].v, oacc[t], 0, 0, 0);
    }
#pragma unroll
    for (int t = 0; t < 4; ++t) {
#pragma unroll
        for (int r = 0; r < 4; ++r) {
            int node = nodeb + wv * 16 + quad * 4 + r;
            if (node < N_NODES)
                out[(size_t)node * OUT_DIM + t * 16 + l16] = oacc[t][r] + bias[t];
        }
    }
}

extern "C" void kernel_launch(void* const* d_in, const int* in_sizes, int n_in,
                              void* d_out, int out_size, void* d_ws, size_t ws_size,
                              hipStream_t stream) {
    const float* x     = (const float*)d_in[0];
    const int*   ei    = (const int*)d_in[1];
    const float* W_lin = (const float*)d_in[2];
    const float* att   = (const float*)d_in[3];
    const float* W_out = (const float*)d_in[4];
    const float* b_out = (const float*)d_in[5];
    float* out = (float*)d_out;

    // workspace layout (~22.4 MB): zp eliminated (out written directly).
    char* ws = (char*)d_ws;
    unsigned* h2        = (unsigned*)(ws);                    // 12,800,000 B (bf16 h)
    float*    s         = (float*)(ws + 12800000);            //    400,000 B
    float*    d         = (float*)(ws + 13200000);            //    400,000 B
    int*      gcount    = (int*)  (ws + 13600000);            //      3,128 B
    unsigned* ibuf      = (unsigned*)(ws + 14800016);         //  7,607,296 B

    hipMemsetAsync(gcount, 0, NB * sizeof(int), stream);

    k1_p1<<<GRID_TOTAL, 256, 0, stream>>>(
        x, W_lin, att, (uint4*)h2, s, d, ei, gcount, ibuf);
    k_sort_agg<<<NB, 512, 0, stream>>>(ibuf, gcount, s, d, (const uint4*)h2,
                                       W_out, b_out, out);
}